// Round 6
// baseline (239.108 us; speedup 1.0000x reference)
//
#include <hip/hip_runtime.h>

#define T_DIM 512
#define B_DIM 4096
#define L_DIM 4
#define LOG2E 1.44269504088896f
#define TWOLOG2E 2.88539008177793f      // 2*log2(e)
#define HALF_LN2 0.346573590279973f     // 1/(2*log2(e)) = ln(2)/2

// DPP move with compile-time ctrl (bound_ctrl=1: OOB lanes read 0).
template <int CTRL>
__device__ __forceinline__ float dpp_mov(float v) {
  int r = __builtin_amdgcn_update_dpp(0, __builtin_bit_cast(int, v), CTRL, 0xf, 0xf, true);
  return __builtin_bit_cast(float, r);
}
template <int CTRL>
__device__ __forceinline__ float qp_add(float v) { return v + dpp_mov<CTRL>(v); }

// ---------------- gate-split layer-skewed fused LSTM -------------------------
// R6: TWO WAVES PER SIMD. 256 blocks x 512 threads = 2048 waves (8 waves/CU,
// 2 per SIMD). R0-R5 ran exactly 1 wave/SIMD; measured decomposition of the
// 355 cy/step wall (chain ~112 cy + issue ~120 cy + residual mem stalls,
// VALUBusy 34%) says the serial cell chain's stall cycles are dead issue
// slots — no compiler scheduling has filled them across 3 rounds of trying.
// With 2 independent waves per SIMD the hardware interleaves them.
//
// Each wave now handles 2 chains: lanes 32-63 MIRROR lanes 0-31
// (c = (lane>>4)&1). Mirroring keeps all DPP row/quad patterns bit-identical
// in both halves (nothing crosses the 32-lane boundary), mirrored loads hit
// the same addresses (coalescer dedups), and duplicate stores are masked
// with lane<32. Block = 8 waves = 16 consecutive chains -> output stores
// still cover full 64B lines (keeps R3's WRITE_SIZE fix).
//
// lane = 16*c' + 4*l + g (c' in 0..3, c = c'&1): layer l, gate g.
// Skew: quad (c,l) is at time t = k - l; h_{l-1}(t) arrives via row_shr:4.
// Layer-0 GEMV: lane loads ONE float x[chain][4l+g]; gate-g's chunk-l dot is
// built with 3 quad_perm rotations + 4 fmas; sum over l-chunks via two
// row_ror DPP butterflies. All off the serial h-chain.
// Gates: 1 exp2 + 1 rcp per lane; all four (i,f,g~,o) gathered with 4
// quad_perm reads so every lane holds valid state. Weights pre-scaled by
// -log2e (i,f,o) / +2log2e (g~); cell state tracked scaled (cse = 2log2e*c)
// so tanh's exp2 consumes it directly.
__global__ __launch_bounds__(512, 2) void lstm_fused(
    const float* __restrict__ x,      // [T,B,16]
    const float* __restrict__ Wih0,   // [4,16]
    const float* __restrict__ Wrest,  // [3,4]
    const float* __restrict__ Whh,    // [4,4]
    const float* __restrict__ bih, const float* __restrict__ bhh,
    float* __restrict__ out) {
  const int tid = threadIdx.x;
  const int lane = tid & 63;
  const int wid = tid >> 6;               // wave id in block, 0..7
  const int g = lane & 3;
  const int l = (lane >> 2) & 3;
  const int c = (lane >> 4) & 1;          // mirrored: lanes 32-63 == 0-31
  const bool primary = lane < 32;         // store-owning half
  const int chain = blockIdx.x * 16 + wid * 2 + c;
  const bool l0 = (l == 0);

  // gate scale: -log2e for sigmoid gates (i,f,o), +2log2e for tanh (g~).
  auto sg = [](int i) { return (i == 2) ? 2.0f * LOG2E : -LOG2E; };

  // recurrent weights for this lane's (l, g)
  const float whh  = sg(g) * Whh[l * 4 + g];
  const float wih  = l0 ? 0.f : sg(g) * Wrest[(l - 1) * 4 + g];
  const float base = l0 ? 0.f : sg(g) * (bih[l * 4 + g] + bhh[l * 4 + g]);

  // rotate-dot weights: round r multiplies x[c][4l+((g+r)&3)] (from the quad
  // rotation) by wq_r = sg(g)*Wih0[g][4l+((g+r)&3)].
  float wq0, wq1, wq2, wq3;
  {
    const float s = sg(g);
    wq0 = s * Wih0[g * 16 + 4 * l + ((g + 0) & 3)];
    wq1 = s * Wih0[g * 16 + 4 * l + ((g + 1) & 3)];
    wq2 = s * Wih0[g * 16 + 4 * l + ((g + 2) & 3)];
    wq3 = s * Wih0[g * 16 + 4 * l + ((g + 3) & 3)];
  }
  // layer-0 bias: only l==0 lanes carry it into the l-reduction (added once).
  const float dinit = l0 ? sg(g) * (bih[g] + bhh[g]) : 0.f;
  // gate post-map: sigmoid lanes v = r; tanh lane v = 2log2e*(1-2r) (scaled).
  const float vm = (g == 2) ? -2.f * TWOLOG2E : 1.f;
  const float va = (g == 2) ? TWOLOG2E : 0.f;

  // x as [T][B*16] floats; lane (c,l,g) reads element chain*16 + 4l + g.
  // Mirrored lanes read identical addresses (dedup'd by the coalescer).
  const float* __restrict__ xp = x + (size_t)chain * 16 + (size_t)(4 * l + g);
  float* __restrict__ po = out + chain;

  float h = 0.f, cse = 0.f;
  float A[8], B[8];                       // constant-indexed only -> VGPRs

#define LOAD8(R, t0)                                                        \
  do {                                                                      \
    R[0] = xp[(size_t)((t0) + 0) * 65536];                                  \
    R[1] = xp[(size_t)((t0) + 1) * 65536];                                  \
    R[2] = xp[(size_t)((t0) + 2) * 65536];                                  \
    R[3] = xp[(size_t)((t0) + 3) * 65536];                                  \
    R[4] = xp[(size_t)((t0) + 4) * 65536];                                  \
    R[5] = xp[(size_t)((t0) + 5) * 65536];                                  \
    R[6] = xp[(size_t)((t0) + 6) * 65536];                                  \
    R[7] = xp[(size_t)((t0) + 7) * 65536];                                  \
  } while (0)

  // layer-0 gate dot from scalar x: pure VALU, no h dependence.
  // quad_perm sel[i]=(i+r)&3: r=1 -> 0x39, r=2 -> 0x4E, r=3 -> 0x93.
  auto dotD = [&](float xv) -> float {
    float x1 = dpp_mov<0x39>(xv);
    float x2 = dpp_mov<0x4E>(xv);
    float x3 = dpp_mov<0x93>(xv);
    float p = fmaf(xv, wq0, dinit);
    p = fmaf(x1, wq1, p);
    p = fmaf(x2, wq2, p);
    p = fmaf(x3, wq3, p);
    p = qp_add<0x124>(p);                  // row_ror:4
    p = qp_add<0x128>(p);                  // row_ror:8 -> full gate-g dot everywhere
    return p;
  };

  auto cellv = [&](int k, float D, bool guard) {
    float hin = dpp_mov<0x114>(h);           // row_shr:4 -> h_{l-1}(t); 0 for l=0
    float pb = l0 ? D : base;
    float gate = fmaf(whh, h, fmaf(wih, hin, pb));

    float r = __builtin_amdgcn_rcpf(1.0f + __builtin_amdgcn_exp2f(gate));
    float v = fmaf(vm, r, va);               // lane g: i, f, 2log2e*g~, o

    float i_  = dpp_mov<0x00>(v);            // quad lane0: i
    float f_  = dpp_mov<0x55>(v);            // quad lane1: f
    float tgs = dpp_mov<0xAA>(v);            // quad lane2: 2log2e*g~
    float o_  = dpp_mov<0xFF>(v);            // quad lane3: o
    float cne = fmaf(f_, cse, i_ * tgs);     // scaled cell state, all lanes
    float tcn = fmaf(-2.0f,
        __builtin_amdgcn_rcpf(1.0f + __builtin_amdgcn_exp2f(cne)), 1.0f);
    float hm = o_ * tcn;                     // valid in ALL lanes

    if (guard) {
      const bool valid = (unsigned)(k - l) < (unsigned)T_DIM;
      cse = valid ? cne : cse;
      h   = valid ? hm : h;
    } else {
      cse = cne; h = hm;
    }
    // store h_3(t) directly from the cell (primary half only)
    const int t = k - 3;
    if (l == 3 && g == 0 && primary && (unsigned)t < (unsigned)T_DIM)
      po[(size_t)t * B_DIM] = hm;
  };

  // Chunk body: phase 1 computes all 8 layer-0 gate dots (independent of h;
  // compiler places counted vmcnt waits per consumed load); phase 2 runs the
  // serial h-chain on precomputed scalars.
#define CELLS8(R, k0, guard)                                                \
  do {                                                                      \
    float D0_ = dotD(R[0]), D1_ = dotD(R[1]), D2_ = dotD(R[2]),             \
          D3_ = dotD(R[3]), D4_ = dotD(R[4]), D5_ = dotD(R[5]),             \
          D6_ = dotD(R[6]), D7_ = dotD(R[7]);                               \
    cellv((k0) + 0, D0_, guard);                                            \
    cellv((k0) + 1, D1_, guard);                                            \
    cellv((k0) + 2, D2_, guard);                                            \
    cellv((k0) + 3, D3_, guard);                                            \
    cellv((k0) + 4, D4_, guard);                                            \
    cellv((k0) + 5, D5_, guard);                                            \
    cellv((k0) + 6, D6_, guard);                                            \
    cellv((k0) + 7, D7_, guard);                                            \
  } while (0)

  // Software pipeline in source order: issue chunk n+1's loads before running
  // chunk n's cells.
  LOAD8(A, 0);
  LOAD8(B, 8);
  CELLS8(A, 0, true);                                    // warm-up k=0..7
#pragma unroll 1
  for (int n = 1; n < 63; n += 2) {
    LOAD8(A, 8 * (n + 1));
    CELLS8(B, 8 * n, false);
    LOAD8(B, 8 * (n + 2));
    CELLS8(A, 8 * (n + 1), false);
  }
  // chunk 63 (k=504..511): B was loaded with t=504 in the last loop iter
  CELLS8(B, 504, false);
  // drain (k=512..519): stale-but-finite xv; guard freezes all state, stores
  // are range-checked (t=509..511 emitted here)
  CELLS8(B, 512, true);

  // hn, cn: every lane of quad (c,l) holds h_l(T-1) and cse_l(T-1)
  if (g == 0 && primary) {
    po[(size_t)T_DIM * B_DIM + (size_t)l * B_DIM] = h;
    po[(size_t)T_DIM * B_DIM + (size_t)L_DIM * B_DIM + (size_t)l * B_DIM] =
        cse * HALF_LN2;                     // unscale once
  }
#undef LOAD8
#undef CELLS8
}

extern "C" void kernel_launch(void* const* d_in, const int* in_sizes, int n_in,
                              void* d_out, int out_size, void* d_ws, size_t ws_size,
                              hipStream_t stream) {
  const float* x     = (const float*)d_in[0];
  const float* Wih0  = (const float*)d_in[1];
  const float* Wrest = (const float*)d_in[2];
  const float* Whh   = (const float*)d_in[3];
  const float* bih   = (const float*)d_in[4];
  const float* bhh   = (const float*)d_in[5];
  float* out = (float*)d_out;
  lstm_fused<<<B_DIM / 16, 512, 0, stream>>>(x, Wih0, Wrest, Whh, bih, bhh, out);
}

// Round 7
// 219.034 us; speedup vs baseline: 1.0917x; 1.0917x over previous
//
#include <hip/hip_runtime.h>

#define T_DIM 512
#define B_DIM 4096
#define L_DIM 4
#define LOG2E 1.44269504088896f
#define TWOLOG2E 2.88539008177793f      // 2*log2(e)
#define HALF_LN2 0.346573590279973f     // 1/(2*log2(e)) = ln(2)/2

// DPP move with compile-time ctrl (bound_ctrl=1: OOB lanes read 0).
template <int CTRL>
__device__ __forceinline__ float dpp_mov(float v) {
  int r = __builtin_amdgcn_update_dpp(0, __builtin_bit_cast(int, v), CTRL, 0xf, 0xf, true);
  return __builtin_bit_cast(float, r);
}
template <int CTRL>
__device__ __forceinline__ float qp_add(float v) { return v + dpp_mov<CTRL>(v); }

// ---------------- gate-split layer-skewed fused LSTM -------------------------
// R7: back to R4 geometry (256 blocks x 256 threads = 1024 waves, 1/SIMD,
// 4 chains/wave) — R6's mirrored 2-wave variant ran identical lockstep
// streams and regressed. Single change this round: CHAIN-SHORTENED CELL.
//
// lane = 16*c + 4*l + g: chain c (16-lane row), layer l, gate g.
// Skew: quad (c,l) is at time t = k - l; h_{l-1}(t) arrives via row_shr:4.
//
// Cell state is kept FACTORED: (tc = tanh(c), og = o-gate); h = og*tc is
// never materialized on the chain. The recurrent contribution is
//   gate = fma(owin, tcin, fma(ow, tc, pb))
// with ow = whh*og and owin = wih*dpp(og) precomputed OFF-CHAIN at the end
// of the previous step (o is ready right after the gate gather, well before
// the tanh completes). On-chain tail: rcp -> tc(fma) -> dpp(tcin) ->
// fma(gate) -> exp2  (was: rcp -> tcn -> hm mul -> dpp(hin) -> fma -> fma ->
// exp2). i/f/o are gathered from r directly (v-map is identity for sigmoid
// lanes); only the g~ lane's scaled affine map stays on the i-path.
// Net: 15 -> 13 dependence levels per step (4 trans irreducible).
//
// Layer-0 GEMV (R4, unchanged): lane loads ONE float x[chain][4l+g]; gate-g's
// chunk-l dot via 3 quad_perm rotations + 4 fmas; chunk-sum via two row_ror
// DPP butterflies. All off the serial h-chain, one chunk prefetched ahead.
// Weights pre-scaled by -log2e (i,f,o) / +2log2e (g~); cell state tracked
// scaled (cse = 2log2e*c) so tanh's exp2 consumes it directly.
__global__ __launch_bounds__(256, 1) void lstm_fused(
    const float* __restrict__ x,      // [T,B,16]
    const float* __restrict__ Wih0,   // [4,16]
    const float* __restrict__ Wrest,  // [3,4]
    const float* __restrict__ Whh,    // [4,4]
    const float* __restrict__ bih, const float* __restrict__ bhh,
    float* __restrict__ out) {
  const int tid = threadIdx.x;
  const int lane = tid & 63;
  const int wid = tid >> 6;               // wave id in block, 0..3
  const int g = lane & 3;
  const int l = (lane >> 2) & 3;
  const int c = (lane >> 4) & 3;
  const int chain = blockIdx.x * 16 + wid * 4 + c;
  const bool l0 = (l == 0);

  // gate scale: -log2e for sigmoid gates (i,f,o), +2log2e for tanh (g~).
  auto sg = [](int i) { return (i == 2) ? 2.0f * LOG2E : -LOG2E; };

  // recurrent weights for this lane's (l, g)
  const float whh  = sg(g) * Whh[l * 4 + g];
  const float wih  = l0 ? 0.f : sg(g) * Wrest[(l - 1) * 4 + g];
  const float base = l0 ? 0.f : sg(g) * (bih[l * 4 + g] + bhh[l * 4 + g]);

  // rotate-dot weights: round r multiplies x[c][4l+((g+r)&3)] (from the quad
  // rotation) by wq_r = sg(g)*Wih0[g][4l+((g+r)&3)].
  float wq0, wq1, wq2, wq3;
  {
    const float s = sg(g);
    wq0 = s * Wih0[g * 16 + 4 * l + ((g + 0) & 3)];
    wq1 = s * Wih0[g * 16 + 4 * l + ((g + 1) & 3)];
    wq2 = s * Wih0[g * 16 + 4 * l + ((g + 2) & 3)];
    wq3 = s * Wih0[g * 16 + 4 * l + ((g + 3) & 3)];
  }
  // layer-0 bias: only l==0 lanes carry it into the l-reduction (added once).
  const float dinit = l0 ? sg(g) * (bih[g] + bhh[g]) : 0.f;
  // gate post-map: sigmoid lanes v = r (identity); tanh lane v = 2log2e*(1-2r).
  const float vm = (g == 2) ? -2.f * TWOLOG2E : 1.f;
  const float va = (g == 2) ? TWOLOG2E : 0.f;

  // x as [T][B*16] floats; lane (c,l,g) reads element chain*16 + 4l + g.
  const float* __restrict__ xp = x + (size_t)chain * 16 + (size_t)(4 * l + g);
  float* __restrict__ po = out + chain;

  // factored recurrent state
  float cse = 0.f;      // scaled cell state (2log2e * c)
  float tc = 0.f;       // tanh(c)
  float og = 0.f;       // o gate
  float ow = 0.f;       // whh * og      (off-chain, prev step)
  float owin = 0.f;     // wih * dpp(og) (off-chain, prev step)
  float A[8], B[8];     // constant-indexed only -> VGPRs

#define LOAD8(R, t0)                                                        \
  do {                                                                      \
    R[0] = xp[(size_t)((t0) + 0) * 65536];                                  \
    R[1] = xp[(size_t)((t0) + 1) * 65536];                                  \
    R[2] = xp[(size_t)((t0) + 2) * 65536];                                  \
    R[3] = xp[(size_t)((t0) + 3) * 65536];                                  \
    R[4] = xp[(size_t)((t0) + 4) * 65536];                                  \
    R[5] = xp[(size_t)((t0) + 5) * 65536];                                  \
    R[6] = xp[(size_t)((t0) + 6) * 65536];                                  \
    R[7] = xp[(size_t)((t0) + 7) * 65536];                                  \
  } while (0)

  // layer-0 gate dot from scalar x: pure VALU, no h dependence.
  // quad_perm sel[i]=(i+r)&3: r=1 -> 0x39, r=2 -> 0x4E, r=3 -> 0x93.
  auto dotD = [&](float xv) -> float {
    float x1 = dpp_mov<0x39>(xv);
    float x2 = dpp_mov<0x4E>(xv);
    float x3 = dpp_mov<0x93>(xv);
    float p = fmaf(xv, wq0, dinit);
    p = fmaf(x1, wq1, p);
    p = fmaf(x2, wq2, p);
    p = fmaf(x3, wq3, p);
    p = qp_add<0x124>(p);                  // row_ror:4
    p = qp_add<0x128>(p);                  // row_ror:8 -> full gate-g dot everywhere
    return p;
  };

  auto cellv = [&](int k, float D, bool guard) {
    // neighbor's tanh(c) as of end of previous step (l0 lanes read 0)
    float tcin = dpp_mov<0x114>(tc);         // ON-CHAIN: the only dpp here
    float pb = l0 ? D : base;
    float inner = fmaf(ow, tc, pb);          // hides under the dpp
    float gate = fmaf(owin, tcin, inner);

    float r = __builtin_amdgcn_rcpf(1.0f + __builtin_amdgcn_exp2f(gate));
    float v = fmaf(vm, r, va);               // only the g~ lane's map matters

    float i_   = dpp_mov<0x00>(r);           // quad lane0: i   (v==r there)
    float f_   = dpp_mov<0x55>(r);           // quad lane1: f   (v==r there)
    float tgs  = dpp_mov<0xAA>(v);           // quad lane2: 2log2e*g~
    float og_n = dpp_mov<0xFF>(r);           // quad lane3: o   (v==r there)
    float cne = fmaf(f_, cse, i_ * tgs);     // scaled cell state, all lanes
    float tc_n = fmaf(-2.0f,
        __builtin_amdgcn_rcpf(1.0f + __builtin_amdgcn_exp2f(cne)), 1.0f);

    if (guard) {
      const bool valid = (unsigned)(k - l) < (unsigned)T_DIM;
      cse = valid ? cne : cse;
      tc  = valid ? tc_n : tc;
      og  = valid ? og_n : og;
    } else {
      cse = cne; tc = tc_n; og = og_n;
    }
    // OFF-CHAIN: next step's o-products. dpp reads the (guarded) updated og,
    // so frozen neighbors are reflected correctly.
    float oin = dpp_mov<0x114>(og);
    ow = whh * og;
    owin = wih * oin;
    // store h_3(t) = og*tc (off-chain mul; equals fresh value when t valid)
    const int t = k - 3;
    if (l == 3 && g == 0 && (unsigned)t < (unsigned)T_DIM)
      po[(size_t)t * B_DIM] = og * tc;
  };

  // Chunk body: phase 1 computes all 8 layer-0 gate dots (independent of h;
  // compiler places counted vmcnt waits per consumed load); phase 2 runs the
  // serial chain on precomputed scalars.
#define CELLS8(R, k0, guard)                                                \
  do {                                                                      \
    float D0_ = dotD(R[0]), D1_ = dotD(R[1]), D2_ = dotD(R[2]),             \
          D3_ = dotD(R[3]), D4_ = dotD(R[4]), D5_ = dotD(R[5]),             \
          D6_ = dotD(R[6]), D7_ = dotD(R[7]);                               \
    cellv((k0) + 0, D0_, guard);                                            \
    cellv((k0) + 1, D1_, guard);                                            \
    cellv((k0) + 2, D2_, guard);                                            \
    cellv((k0) + 3, D3_, guard);                                            \
    cellv((k0) + 4, D4_, guard);                                            \
    cellv((k0) + 5, D5_, guard);                                            \
    cellv((k0) + 6, D6_, guard);                                            \
    cellv((k0) + 7, D7_, guard);                                            \
  } while (0)

  // Software pipeline in source order: issue chunk n+1's loads before running
  // chunk n's cells.
  LOAD8(A, 0);
  LOAD8(B, 8);
  CELLS8(A, 0, true);                                    // warm-up k=0..7
#pragma unroll 1
  for (int n = 1; n < 63; n += 2) {
    LOAD8(A, 8 * (n + 1));
    CELLS8(B, 8 * n, false);
    LOAD8(B, 8 * (n + 2));
    CELLS8(A, 8 * (n + 1), false);
  }
  // chunk 63 (k=504..511): B was loaded with t=504 in the last loop iter
  CELLS8(B, 504, false);
  // drain (k=512..519): stale-but-finite xv; guard freezes all state, stores
  // are range-checked (t=509..511 emitted here)
  CELLS8(B, 512, true);

  // hn, cn: every lane of quad (c,l) holds (og,tc,cse) of its layer at T-1
  if (g == 0) {
    po[(size_t)T_DIM * B_DIM + (size_t)l * B_DIM] = og * tc;
    po[(size_t)T_DIM * B_DIM + (size_t)L_DIM * B_DIM + (size_t)l * B_DIM] =
        cse * HALF_LN2;                     // unscale once
  }
#undef LOAD8
#undef CELLS8
}

extern "C" void kernel_launch(void* const* d_in, const int* in_sizes, int n_in,
                              void* d_out, int out_size, void* d_ws, size_t ws_size,
                              hipStream_t stream) {
  const float* x     = (const float*)d_in[0];
  const float* Wih0  = (const float*)d_in[1];
  const float* Wrest = (const float*)d_in[2];
  const float* Whh   = (const float*)d_in[3];
  const float* bih   = (const float*)d_in[4];
  const float* bhh   = (const float*)d_in[5];
  float* out = (float*)d_out;
  lstm_fused<<<B_DIM / 16, 256, 0, stream>>>(x, Wih0, Wrest, Whh, bih, bhh, out);
}